// Round 1
// baseline (118.353 us; speedup 1.0000x reference)
//
#include <hip/hip_runtime.h>
#include <cstdint>
#include <climits>
#include <cmath>

#define ALPHA 0.7f
#define SIGMA 0.1f
#define MIN_MINING_STEP 50

constexpr int TT   = 2048;       // sequence length (fixed by problem)
constexpr int NTH  = 256;        // threads per block
constexpr int EPT  = TT / NTH;   // 8 elements per thread
constexpr int NWAVE = NTH / 64;  // 4 waves per block

// Inclusive max-scan over TT elements distributed as EPT consecutive
// elements per thread. Two-level: serial-local + wave shfl + cross-wave LDS.
__device__ __forceinline__ void maxscan_block(int (&v)[EPT], int* sWaveTot) {
    const int tid  = threadIdx.x;
    const int lane = tid & 63;
    const int wid  = tid >> 6;
#pragma unroll
    for (int k = 1; k < EPT; ++k) v[k] = max(v[k], v[k - 1]);
    int tot = v[EPT - 1];
#pragma unroll
    for (int off = 1; off < 64; off <<= 1) {
        int n = __shfl_up(tot, off);
        if (lane >= off) tot = max(tot, n);
    }
    if (lane == 63) sWaveTot[wid] = tot;
    __syncthreads();
    int excl = INT_MIN;
    for (int w = 0; w < wid; ++w) excl = max(excl, sWaveTot[w]);
    int up = __shfl_up(tot, 1);
    if (lane > 0) excl = max(excl, up);
#pragma unroll
    for (int k = 0; k < EPT; ++k) v[k] = max(v[k], excl);
    __syncthreads();   // protect sWaveTot for the next call
}

__device__ __forceinline__ float waveRedMin(float v) {
#pragma unroll
    for (int off = 32; off > 0; off >>= 1) v = fminf(v, __shfl_xor(v, off));
    return v;
}
__device__ __forceinline__ float waveRedMax(float v) {
#pragma unroll
    for (int off = 32; off > 0; off >>= 1) v = fmaxf(v, __shfl_xor(v, off));
    return v;
}
__device__ __forceinline__ float waveRedSum(float v) {
#pragma unroll
    for (int off = 32; off > 0; off >>= 1) v += __shfl_xor(v, off);
    return v;
}

// One block per abnormal row b (b < nb). Does: sigmoid+crop-mean, mining
// (two directions, scan-based), mask compaction, gaussian splat via
// min-distance, min-max normalize, BCE loss partial sum.
__global__ __launch_bounds__(NTH) void glance_row(
    const float* __restrict__ scores,       // (B*C, T)
    const int*   __restrict__ point_label,  // (B, T)
    const int*   __restrict__ seqlen,       // (B,)
    const int*   __restrict__ step_p,       // (1,)
    float*       __restrict__ partial,      // (nb,)
    int C)
{
    __shared__ float sS[TT];                // probs (crop-mean of sigmoids)
    __shared__ int   sA[TT];                // anchors (point labels > 0)
    __shared__ int   sMask[TT];             // mined mask
    __shared__ int   sLa[TT];               // last-anchor scan (direction-local)
    __shared__ unsigned short sList[TT];    // compacted mask indices
    __shared__ int   sWave[NWAVE];
    __shared__ float sRedA[NWAVE], sRedB[NWAVE];
    __shared__ int   sCount;

    const int b    = blockIdx.x;
    const int tid  = threadIdx.x;
    const int lane = tid & 63;
    const int wid  = tid >> 6;

    if (tid == 0) sCount = 0;

    // ---- load + sigmoid + crop mean ----
    const float invC = 1.0f / (float)C;
    for (int t = tid; t < TT; t += NTH) {
        float acc = 0.0f;
        for (int c = 0; c < C; ++c) {
            float x = scores[(size_t)(b * C + c) * TT + t];
            acc += 1.0f / (1.0f + expf(-x));
        }
        sS[t] = acc * invC;
        int a = (point_label[(size_t)b * TT + t] > 0) ? 1 : 0;
        sA[t]    = a;
        sMask[t] = a;
    }
    const int stepv = step_p[0];
    const int vlen  = seqlen[b];
    __syncthreads();

    const int j0 = tid * EPT;

    // ---- mining: g[j] = (lastAnchorBefore(j) >= 0) && lastFail(j) <= lastAnchorBefore(j)
    if (stepv >= MIN_MINING_STEP) {
        for (int dir = 0; dir < 2; ++dir) {
            // pass 1: inclusive max-scan of (anchor ? j : -1)  (direction-local j)
            int v[EPT];
#pragma unroll
            for (int k = 0; k < EPT; ++k) {
                int j = j0 + k;
                int t = dir ? (TT - 1 - j) : j;
                v[k] = sA[t] ? j : -1;
            }
            maxscan_block(v, sWave);
#pragma unroll
            for (int k = 0; k < EPT; ++k) sLa[j0 + k] = v[k];
            __syncthreads();

            // pass 2: per-element condition vs segment anchor, then fail-index max-scan
            int q[EPT], f[EPT];
#pragma unroll
            for (int k = 0; k < EPT; ++k) {
                int j  = j0 + k;
                int qq = (j > 0) ? sLa[j - 1] : -1;   // last anchor strictly before j
                bool c = false;
                if (qq >= 0) {
                    int t  = dir ? (TT - 1 - j)  : j;
                    int tq = dir ? (TT - 1 - qq) : qq;
                    c = sS[t] >= ALPHA * sS[tq];
                }
                q[k] = qq;
                f[k] = c ? -1 : j;
            }
            maxscan_block(f, sWave);
#pragma unroll
            for (int k = 0; k < EPT; ++k) {
                int j = j0 + k;
                bool g = (q[k] >= 0) && (f[k] <= q[k]);
                if (dir == 0) g = g && (j < vlen);    // valid-len applies to fwd only
                if (g) sMask[dir ? (TT - 1 - j) : j] = 1;
            }
            __syncthreads();
        }
    }

    // ---- compact mask indices ----
    for (int t = tid; t < TT; t += NTH) {
        if (sMask[t]) { int idx = atomicAdd(&sCount, 1); sList[idx] = (unsigned short)t; }
    }
    __syncthreads();
    const int A = sCount;

    // ---- splat: temp[i] = exp(-K * minDist^2); per-anchor norm term m_p <= 2e-22, ignored
    float tempv[EPT];
    float tmn = INFINITY, tmx = -INFINITY;
    if (A > 0) {
        int bdd[EPT];
#pragma unroll
        for (int k = 0; k < EPT; ++k) bdd[k] = INT_MAX;
        for (int l = 0; l < A; ++l) {
            int p = (int)sList[l];
#pragma unroll
            for (int k = 0; k < EPT; ++k) {
                int d = (j0 + k) - p;
                bdd[k] = min(bdd[k], d * d);
            }
        }
        const float KK = 2.0f / ((float)(TT - 1) * (float)(TT - 1) * SIGMA * SIGMA);
#pragma unroll
        for (int k = 0; k < EPT; ++k) {
            float tv = expf(-KK * (float)bdd[k]);
            tempv[k] = tv;
            tmn = fminf(tmn, tv);
            tmx = fmaxf(tmx, tv);
        }
        tmn = waveRedMin(tmn);
        tmx = waveRedMax(tmx);
        if (lane == 0) { sRedA[wid] = tmn; sRedB[wid] = tmx; }
        __syncthreads();
        tmn = sRedA[0]; tmx = sRedB[0];
        for (int w = 1; w < NWAVE; ++w) {
            tmn = fminf(tmn, sRedA[w]);
            tmx = fmaxf(tmx, sRedB[w]);
        }
        __syncthreads();   // sRedA/B reused below
    }

    // ---- rendered + BCE loss partial ----
    const bool norm = (A > 0) && (tmx > tmn);
    const float inv = norm ? 1.0f / (tmx - tmn) : 0.0f;
    float lsum = 0.0f;
#pragma unroll
    for (int k = 0; k < EPT; ++k) {
        int i = j0 + k;
        float r = 0.0f;
        if (A > 0) r = norm ? (tempv[k] - tmn) * inv : tempv[k];
        float s = sS[i];
        lsum += -(r * logf(s) + (1.0f - r) * log1pf(-s));
    }
    lsum = waveRedSum(lsum);
    if (lane == 0) sRedA[wid] = lsum;
    __syncthreads();
    if (tid == 0) {
        float tot = 0.0f;
        for (int w = 0; w < NWAVE; ++w) tot += sRedA[w];
        partial[b] = tot;
    }
}

__global__ __launch_bounds__(64) void glance_reduce(
    const float* __restrict__ partial, float* __restrict__ out, int nb, float invN)
{
    float v = ((int)threadIdx.x < nb) ? partial[threadIdx.x] : 0.0f;
#pragma unroll
    for (int off = 32; off > 0; off >>= 1) v += __shfl_down(v, off);
    if (threadIdx.x == 0) out[0] = v * invN;
}

extern "C" void kernel_launch(void* const* d_in, const int* in_sizes, int n_in,
                              void* d_out, int out_size, void* d_ws, size_t ws_size,
                              hipStream_t stream) {
    (void)n_in; (void)out_size; (void)ws_size;
    const float* scores      = (const float*)d_in[0];
    // d_in[1] = labels (unused by the reference computation)
    const int*   point_label = (const int*)d_in[2];
    const int*   seqlen      = (const int*)d_in[3];
    const int*   step_p      = (const int*)d_in[4];

    const int B  = in_sizes[1];            // labels has B elements (64)
    const int T  = in_sizes[2] / B;        // 2048 (kernel assumes TT==2048)
    const int C  = in_sizes[0] / (B * T);  // 2
    const int nb = B / 2;                  // 32

    float* partial = (float*)d_ws;

    glance_row<<<nb, NTH, 0, stream>>>(scores, point_label, seqlen, step_p, partial, C);
    glance_reduce<<<1, 64, 0, stream>>>(partial, (float*)d_out, nb, 1.0f / (float)(nb * T));
}

// Round 2
// 69.911 us; speedup vs baseline: 1.6929x; 1.6929x over previous
//
#include <hip/hip_runtime.h>
#include <cstdint>
#include <climits>
#include <cmath>

#define ALPHA 0.7f
#define SIGMA 0.1f
#define MIN_MINING_STEP 50

constexpr int TT    = 2048;      // sequence length (fixed by problem)
constexpr int NTH   = 256;       // threads per block
constexpr int EPT   = TT / NTH;  // 8 elements per thread
constexpr int NWAVE = NTH / 64;  // 4 waves per block

// Dual inclusive max-scan over TT elements (EPT consecutive per thread).
// v = forward-ordered lane, w = independent second lane (we use it for the
// reversed direction). Also returns each thread's exclusive prefix (i.e. the
// inclusive value at element j0-1), so callers never need an LDS round-trip
// to fetch scan[j-1]. Two internal barriers protect sW reuse across calls.
__device__ __forceinline__ void dual_maxscan(int (&v)[EPT], int (&w)[EPT],
                                             int& exV, int& exW, int* sW) {
    const int tid = threadIdx.x, lane = tid & 63, wid = tid >> 6;
#pragma unroll
    for (int k = 1; k < EPT; ++k) {
        v[k] = max(v[k], v[k - 1]);
        w[k] = max(w[k], w[k - 1]);
    }
    int tv = v[EPT - 1], tw = w[EPT - 1];
#pragma unroll
    for (int off = 1; off < 64; off <<= 1) {
        int nv = __shfl_up(tv, off), nw = __shfl_up(tw, off);
        if (lane >= off) { tv = max(tv, nv); tw = max(tw, nw); }
    }
    if (lane == 63) { sW[wid] = tv; sW[NWAVE + wid] = tw; }
    __syncthreads();
    int ev = INT_MIN, ew = INT_MIN;
    for (int q = 0; q < wid; ++q) {
        ev = max(ev, sW[q]);
        ew = max(ew, sW[NWAVE + q]);
    }
    int uv = __shfl_up(tv, 1), uw = __shfl_up(tw, 1);
    if (lane > 0) { ev = max(ev, uv); ew = max(ew, uw); }
    exV = ev; exW = ew;
#pragma unroll
    for (int k = 0; k < EPT; ++k) {
        v[k] = max(v[k], ev);
        w[k] = max(w[k], ew);
    }
    __syncthreads();   // protect sW for the next call
}

__device__ __forceinline__ float waveRedMin(float v) {
#pragma unroll
    for (int off = 32; off > 0; off >>= 1) v = fminf(v, __shfl_xor(v, off));
    return v;
}
__device__ __forceinline__ float waveRedSum(float v) {
#pragma unroll
    for (int off = 32; off > 0; off >>= 1) v += __shfl_xor(v, off);
    return v;
}

// One block per abnormal row. sigmoid+crop-mean -> scan-based mining ->
// scan-based nearest-anchor distance -> splat -> min-max norm -> BCE ->
// device-wide atomic finish (no second kernel).
__global__ __launch_bounds__(NTH) void glance_fused(
    const float* __restrict__ scores,       // (B*C, T)
    const int*   __restrict__ point_label,  // (B, T)
    const int*   __restrict__ seqlen,       // (B,)
    const int*   __restrict__ step_p,       // (1,)
    float*        wsF,                      // accumulator (pre-zeroed)
    unsigned int* wsC,                      // counter (pre-zeroed)
    float* __restrict__ out,                // (1,)
    int C, int nb, float invN)
{
    __shared__ float sS[TT];        // probs (crop-mean of sigmoids)
    __shared__ int   sM[TT];        // anchors -> mask -> (reused) bwd distance
    __shared__ int   sW[2 * NWAVE];
    __shared__ float sR[NWAVE];
    __shared__ int   sAny;

    const int b = blockIdx.x, tid = threadIdx.x, lane = tid & 63, wid = tid >> 6;

    // ---- load + sigmoid + crop mean (float4/int4 vectorized) ----
    const float invC = 1.0f / (float)C;
    for (int q4 = tid; q4 < TT / 4; q4 += NTH) {
        float4 acc = make_float4(0.f, 0.f, 0.f, 0.f);
        for (int c = 0; c < C; ++c) {
            const float4 x = ((const float4*)(scores + ((size_t)(b * C + c)) * TT))[q4];
            acc.x += 1.0f / (1.0f + __expf(-x.x));
            acc.y += 1.0f / (1.0f + __expf(-x.y));
            acc.z += 1.0f / (1.0f + __expf(-x.z));
            acc.w += 1.0f / (1.0f + __expf(-x.w));
        }
        const int4 p = ((const int4*)(point_label + (size_t)b * TT))[q4];
        const int t = q4 * 4;
        sS[t + 0] = acc.x * invC;  sM[t + 0] = (p.x > 0) ? 1 : 0;
        sS[t + 1] = acc.y * invC;  sM[t + 1] = (p.y > 0) ? 1 : 0;
        sS[t + 2] = acc.z * invC;  sM[t + 2] = (p.z > 0) ? 1 : 0;
        sS[t + 3] = acc.w * invC;  sM[t + 3] = (p.w > 0) ? 1 : 0;
    }
    const int stepv = step_p[0];
    const int vlen  = seqlen[b];
    __syncthreads();

    const int j0 = tid * EPT;

    // ---- mining (both directions fused into dual scans) ----
    // g[j] = lastAnchorBefore(j) >= 0  &&  lastFail(<=j) <= lastAnchorBefore(j)
    if (stepv >= MIN_MINING_STEP) {
        // pass 1: last-anchor-index scan. v: t=j (fwd); w: t=TT-1-j (bwd coords)
        int va[EPT], wa[EPT]; int exA, exB;
#pragma unroll
        for (int k = 0; k < EPT; ++k) {
            const int j = j0 + k;
            va[k] = sM[j] ? j : -1;
            wa[k] = sM[TT - 1 - j] ? j : -1;
        }
        dual_maxscan(va, wa, exA, exB, sW);

        // pass 2: last-fail-index scan (cond vs segment anchor, per element)
        int vf[EPT], wf[EPT]; int exF, exG;
        int qf[EPT], qb[EPT];
#pragma unroll
        for (int k = 0; k < EPT; ++k) {
            const int j  = j0 + k;
            const int qF = (k == 0) ? exA : va[k - 1];   // anchor strictly before j
            const int qB = (k == 0) ? exB : wa[k - 1];
            qf[k] = qF; qb[k] = qB;
            bool cF = false, cB = false;
            if (qF >= 0) cF = sS[j]          >= ALPHA * sS[qF];
            if (qB >= 0) cB = sS[TT - 1 - j] >= ALPHA * sS[TT - 1 - qB];
            vf[k] = cF ? -1 : j;
            wf[k] = cB ? -1 : j;
        }
        dual_maxscan(vf, wf, exF, exG, sW);

        // mask writes (benign 1-races; barriers inside scans ordered the reads)
#pragma unroll
        for (int k = 0; k < EPT; ++k) {
            const int j = j0 + k;
            const bool gF = (qf[k] >= 0) && (vf[k] <= qf[k]) && (j < vlen);
            const bool gB = (qb[k] >= 0) && (wf[k] <= qb[k]);
            if (gF) sM[j] = 1;
            if (gB) sM[TT - 1 - j] = 1;
        }
        __syncthreads();
    }

    // ---- nearest-mask distance via dual scan (replaces O(A*T) splat loop) ----
    int vn[EPT], wn[EPT]; int exN, exO;
#pragma unroll
    for (int k = 0; k < EPT; ++k) {
        const int j = j0 + k;
        vn[k] = sM[j] ? j : -1;
        wn[k] = sM[TT - 1 - j] ? j : -1;
    }
    dual_maxscan(vn, wn, exN, exO, sW);

    // store bwd distance (next mask at/after t) into sM (safe: all sM reads done)
#pragma unroll
    for (int k = 0; k < EPT; ++k) {
        const int j  = j0 + k;
        const int dB = (wn[k] >= 0) ? min(j - wn[k], 4096) : 4096;
        sM[TT - 1 - j] = dB;
    }
    if (tid == NTH - 1) sAny = (vn[EPT - 1] >= 0) ? 1 : 0;  // global last mask idx
    __syncthreads();

    // ---- temp[i] = exp(-K*minDist^2); per-anchor norm term m_p <= 2e-22, ignored
    // tmax == 1 exactly when any mask exists (dist 0 at a masked position)
    const float KK = 2.0f / ((float)(TT - 1) * (float)(TT - 1) * SIGMA * SIGMA);
    float tempv[EPT];
    float tmn = INFINITY;
#pragma unroll
    for (int k = 0; k < EPT; ++k) {
        const int j  = j0 + k;
        const int dF = (vn[k] >= 0) ? min(j - vn[k], 4096) : 4096;
        const int d  = min(dF, sM[j]);
        const float tv = __expf(-KK * (float)(d * d));
        tempv[k] = tv;
        tmn = fminf(tmn, tv);
    }
    tmn = waveRedMin(tmn);
    if (lane == 0) sR[wid] = tmn;
    __syncthreads();
    tmn = sR[0];
    for (int w = 1; w < NWAVE; ++w) tmn = fminf(tmn, sR[w]);
    __syncthreads();   // sR reused below

    // ---- rendered + BCE partial ----
    const bool any  = (sAny != 0);
    const bool norm = any && (tmn < 1.0f);
    const float inv = norm ? 1.0f / (1.0f - tmn) : 0.0f;
    float lsum = 0.0f;
#pragma unroll
    for (int k = 0; k < EPT; ++k) {
        float r = 0.0f;
        if (any) r = norm ? (tempv[k] - tmn) * inv : tempv[k];
        const float s = sS[j0 + k];
        lsum += -(r * __logf(s) + (1.0f - r) * __logf(1.0f - s));
    }
    lsum = waveRedSum(lsum);
    if (lane == 0) sR[wid] = lsum;
    __syncthreads();

    if (tid == 0) {
        float tot = 0.0f;
        for (int w = 0; w < NWAVE; ++w) tot += sR[w];
        atomicAdd(wsF, tot);               // device-scope f32 atomic
        __threadfence();                   // order float-add before counter-inc
        const unsigned int c = atomicAdd(wsC, 1u);
        if (c == (unsigned int)(nb - 1)) {
            // RMW re-read: serialized at coherent point after all 32 adds
            const float total = atomicAdd(wsF, 0.0f);
            out[0] = total * invN;
        }
    }
}

extern "C" void kernel_launch(void* const* d_in, const int* in_sizes, int n_in,
                              void* d_out, int out_size, void* d_ws, size_t ws_size,
                              hipStream_t stream) {
    (void)n_in; (void)out_size; (void)ws_size;
    const float* scores      = (const float*)d_in[0];
    // d_in[1] = labels (unused by the reference computation)
    const int*   point_label = (const int*)d_in[2];
    const int*   seqlen      = (const int*)d_in[3];
    const int*   step_p      = (const int*)d_in[4];

    const int B  = in_sizes[1];            // labels has B elements (64)
    const int T  = in_sizes[2] / B;        // 2048 (kernel assumes TT==2048)
    const int C  = in_sizes[0] / (B * T);  // 2
    const int nb = B / 2;                  // 32

    float*        wsF = (float*)d_ws;
    unsigned int* wsC = (unsigned int*)d_ws + 1;
    hipMemsetAsync(d_ws, 0, 8, stream);    // zero accumulator + counter

    glance_fused<<<nb, NTH, 0, stream>>>(scores, point_label, seqlen, step_p,
                                         wsF, wsC, (float*)d_out,
                                         C, nb, 1.0f / (float)(nb * T));
}

// Round 3
// 67.824 us; speedup vs baseline: 1.7450x; 1.0308x over previous
//
#include <hip/hip_runtime.h>
#include <cstdint>
#include <climits>
#include <cmath>

#define ALPHA 0.7f
#define SIGMA 0.1f
#define MIN_MINING_STEP 50

constexpr int TT    = 2048;      // sequence length (fixed by problem)
constexpr int NTH   = 512;       // threads per block
constexpr int EPT   = TT / NTH;  // 4 elements per thread
constexpr int NWAVE = NTH / 64;  // 8 waves per block

// Dual inclusive max-scan over TT elements (EPT consecutive per thread).
// v = forward lane, w = independent reversed lane. exV/exW return the
// exclusive prefix at this thread's first element. ONE internal barrier;
// caller passes a dedicated sW region (2*NWAVE ints) per call so no
// trailing barrier is needed to protect reuse.
__device__ __forceinline__ void dual_maxscan(int (&v)[EPT], int (&w)[EPT],
                                             int& exV, int& exW, int* sW) {
    const int tid = threadIdx.x, lane = tid & 63, wid = tid >> 6;
#pragma unroll
    for (int k = 1; k < EPT; ++k) {
        v[k] = max(v[k], v[k - 1]);
        w[k] = max(w[k], w[k - 1]);
    }
    int tv = v[EPT - 1], tw = w[EPT - 1];
#pragma unroll
    for (int off = 1; off < 64; off <<= 1) {
        int nv = __shfl_up(tv, off), nw = __shfl_up(tw, off);
        if (lane >= off) { tv = max(tv, nv); tw = max(tw, nw); }
    }
    if (lane == 63) { sW[wid] = tv; sW[NWAVE + wid] = tw; }
    __syncthreads();
    int ev = INT_MIN, ew = INT_MIN;
    for (int q = 0; q < wid; ++q) {
        ev = max(ev, sW[q]);
        ew = max(ew, sW[NWAVE + q]);
    }
    int uv = __shfl_up(tv, 1), uw = __shfl_up(tw, 1);
    if (lane > 0) { ev = max(ev, uv); ew = max(ew, uw); }
    exV = ev; exW = ew;
#pragma unroll
    for (int k = 0; k < EPT; ++k) {
        v[k] = max(v[k], ev);
        w[k] = max(w[k], ew);
    }
}

__device__ __forceinline__ float waveRedMin(float v) {
#pragma unroll
    for (int off = 32; off > 0; off >>= 1) v = fminf(v, __shfl_xor(v, off));
    return v;
}
__device__ __forceinline__ float waveRedSum(float v) {
#pragma unroll
    for (int off = 32; off > 0; off >>= 1) v += __shfl_xor(v, off);
    return v;
}

// One block per abnormal row. sigmoid+crop-mean -> scan-based mining ->
// scan-based nearest-anchor distance -> splat -> min-max norm -> BCE ->
// per-row partial to global. 8 barriers total.
__global__ __launch_bounds__(NTH) void glance_fused(
    const float* __restrict__ scores,       // (B*C, T)
    const int*   __restrict__ point_label,  // (B, T)
    const int*   __restrict__ seqlen,       // (B,)
    const int*   __restrict__ step_p,       // (1,)
    float*       __restrict__ partial,      // (nb,)
    int C)
{
    __shared__ float sS[TT];           // probs (crop-mean of sigmoids)
    __shared__ int   sM[TT];           // anchors -> mask -> (reused) bwd distance
    __shared__ int   sW[6 * NWAVE];    // 3 scan calls x (2*NWAVE) rotating regions
    __shared__ float sRmin[NWAVE];
    __shared__ float sRsum[NWAVE];

    const int b = blockIdx.x, tid = threadIdx.x, lane = tid & 63, wid = tid >> 6;

    // ---- load + sigmoid + crop mean (float4/int4 vectorized; 1 iter/thread) ----
    const float invC = 1.0f / (float)C;
    for (int q4 = tid; q4 < TT / 4; q4 += NTH) {
        float4 acc = make_float4(0.f, 0.f, 0.f, 0.f);
        for (int c = 0; c < C; ++c) {
            const float4 x = ((const float4*)(scores + ((size_t)(b * C + c)) * TT))[q4];
            acc.x += 1.0f / (1.0f + __expf(-x.x));
            acc.y += 1.0f / (1.0f + __expf(-x.y));
            acc.z += 1.0f / (1.0f + __expf(-x.z));
            acc.w += 1.0f / (1.0f + __expf(-x.w));
        }
        const int4 p = ((const int4*)(point_label + (size_t)b * TT))[q4];
        const int t = q4 * 4;
        sS[t + 0] = acc.x * invC;  sM[t + 0] = (p.x > 0) ? 1 : 0;
        sS[t + 1] = acc.y * invC;  sM[t + 1] = (p.y > 0) ? 1 : 0;
        sS[t + 2] = acc.z * invC;  sM[t + 2] = (p.z > 0) ? 1 : 0;
        sS[t + 3] = acc.w * invC;  sM[t + 3] = (p.w > 0) ? 1 : 0;
    }
    const int stepv = step_p[0];
    const int vlen  = seqlen[b];
    __syncthreads();                                          // B1

    const int j0 = tid * EPT;

    // ---- mining (both directions fused into dual scans) ----
    // g[j] = lastAnchorBefore(j) >= 0 && lastFail(<=j) <= lastAnchorBefore(j)
    if (stepv >= MIN_MINING_STEP) {
        // pass 1: last-anchor-index scan. v: t=j (fwd); w: t=TT-1-j (bwd coords)
        int va[EPT], wa[EPT]; int exA, exB;
#pragma unroll
        for (int k = 0; k < EPT; ++k) {
            const int j = j0 + k;
            va[k] = sM[j] ? j : -1;
            wa[k] = sM[TT - 1 - j] ? j : -1;
        }
        dual_maxscan(va, wa, exA, exB, sW);                   // B2

        // pass 2: last-fail-index scan (cond vs segment anchor, per element)
        int vf[EPT], wf[EPT]; int exF, exG;
        int qf[EPT], qb[EPT];
#pragma unroll
        for (int k = 0; k < EPT; ++k) {
            const int j  = j0 + k;
            const int qF = (k == 0) ? exA : va[k - 1];   // anchor strictly before j
            const int qB = (k == 0) ? exB : wa[k - 1];
            qf[k] = qF; qb[k] = qB;
            bool cF = false, cB = false;
            if (qF >= 0) cF = sS[j]          >= ALPHA * sS[qF];
            if (qB >= 0) cB = sS[TT - 1 - j] >= ALPHA * sS[TT - 1 - qB];
            vf[k] = cF ? -1 : j;
            wf[k] = cB ? -1 : j;
        }
        dual_maxscan(vf, wf, exF, exG, sW + 2 * NWAVE);       // B3

        // mask writes (benign 1-races; scan barrier ordered the sS/sM reads)
#pragma unroll
        for (int k = 0; k < EPT; ++k) {
            const int j = j0 + k;
            const bool gF = (qf[k] >= 0) && (vf[k] <= qf[k]) && (j < vlen);
            const bool gB = (qb[k] >= 0) && (wf[k] <= qb[k]);
            if (gF) sM[j] = 1;
            if (gB) sM[TT - 1 - j] = 1;
        }
        __syncthreads();                                      // B4
    }

    // ---- nearest-mask distance via dual scan ----
    int vn[EPT], wn[EPT]; int exN, exO;
#pragma unroll
    for (int k = 0; k < EPT; ++k) {
        const int j = j0 + k;
        vn[k] = sM[j] ? j : -1;
        wn[k] = sM[TT - 1 - j] ? j : -1;
    }
    dual_maxscan(vn, wn, exN, exO, sW + 4 * NWAVE);           // B5

    // exchange bwd distance (next mask at/after t) through sM
    // (sM input reads all happened before B5; these writes are after it)
#pragma unroll
    for (int k = 0; k < EPT; ++k) {
        const int j  = j0 + k;
        const int dB = (wn[k] >= 0) ? min(j - wn[k], 4096) : 4096;
        sM[TT - 1 - j] = dB;
    }
    // any-mask flag: global last fwd mask index lives in thread NTH-1's vn tail;
    // cheaper: any thread's (vn,wn) pair covers the whole row: max(vn,ex0-side).
    // Use: row has a mask iff max over all = >=0. Thread-local test via scan
    // result at last element of row is only in last thread -> broadcast via sW.
    if (tid == NTH - 1) sW[0] = (vn[EPT - 1] >= 0) ? 1 : 0;
    __syncthreads();                                          // B6
    const bool any = (sW[0] != 0);

    // ---- temp[i] = exp(-K*minDist^2); per-anchor norm term m_p <= 2e-22 ignored.
    // tmax == 1 exactly when any mask exists (dist 0 at a masked position).
    const float KK = 2.0f / ((float)(TT - 1) * (float)(TT - 1) * SIGMA * SIGMA);
    float tempv[EPT];
    float tmn = INFINITY;
#pragma unroll
    for (int k = 0; k < EPT; ++k) {
        const int j  = j0 + k;
        const int dF = (vn[k] >= 0) ? min(j - vn[k], 4096) : 4096;
        const int d  = min(dF, sM[j]);
        const float tv = __expf(-KK * (float)(d * d));
        tempv[k] = tv;
        tmn = fminf(tmn, tv);
    }
    tmn = waveRedMin(tmn);
    if (lane == 0) sRmin[wid] = tmn;
    __syncthreads();                                          // B7
    tmn = sRmin[0];
    for (int w = 1; w < NWAVE; ++w) tmn = fminf(tmn, sRmin[w]);

    // ---- rendered + BCE partial ----
    const bool norm = any && (tmn < 1.0f);
    const float inv = norm ? 1.0f / (1.0f - tmn) : 0.0f;
    float lsum = 0.0f;
#pragma unroll
    for (int k = 0; k < EPT; ++k) {
        float r = 0.0f;
        if (any) r = norm ? (tempv[k] - tmn) * inv : tempv[k];
        const float s = sS[j0 + k];
        lsum += -(r * __logf(s) + (1.0f - r) * __logf(1.0f - s));
    }
    lsum = waveRedSum(lsum);
    if (lane == 0) sRsum[wid] = lsum;   // separate region: no race with sRmin reads
    __syncthreads();                                          // B8
    if (tid == 0) {
        float tot = 0.0f;
        for (int w = 0; w < NWAVE; ++w) tot += sRsum[w];
        partial[b] = tot;
    }
}

// Kernel boundary provides cross-XCD ordering/coherence for partial[].
__global__ __launch_bounds__(64) void glance_reduce(
    const float* __restrict__ partial, float* __restrict__ out, int nb, float invN)
{
    float v = ((int)threadIdx.x < nb) ? partial[threadIdx.x] : 0.0f;
#pragma unroll
    for (int off = 32; off > 0; off >>= 1) v += __shfl_down(v, off);
    if (threadIdx.x == 0) out[0] = v * invN;
}

extern "C" void kernel_launch(void* const* d_in, const int* in_sizes, int n_in,
                              void* d_out, int out_size, void* d_ws, size_t ws_size,
                              hipStream_t stream) {
    (void)n_in; (void)out_size; (void)ws_size;
    const float* scores      = (const float*)d_in[0];
    // d_in[1] = labels (unused by the reference computation)
    const int*   point_label = (const int*)d_in[2];
    const int*   seqlen      = (const int*)d_in[3];
    const int*   step_p      = (const int*)d_in[4];

    const int B  = in_sizes[1];            // labels has B elements (64)
    const int T  = in_sizes[2] / B;        // 2048 (kernel assumes TT==2048)
    const int C  = in_sizes[0] / (B * T);  // 2
    const int nb = B / 2;                  // 32

    float* partial = (float*)d_ws;

    glance_fused<<<nb, NTH, 0, stream>>>(scores, point_label, seqlen, step_p,
                                         partial, C);
    glance_reduce<<<1, 64, 0, stream>>>(partial, (float*)d_out, nb,
                                        1.0f / (float)(nb * T));
}